// Round 1
// baseline (4166.473 us; speedup 1.0000x reference)
//
#include <hip/hip_runtime.h>
#include <hip/hip_bf16.h>

// Problem constants (HybridTextClassifier)
// B=16, S=256, V=32000, E=256, H=8, L=2, FFN=1024, NC=4, DK=32, NQ=256

__device__ __forceinline__ unsigned short f2bf(float f) {
  unsigned u = __builtin_bit_cast(unsigned, f);
  u += 0x7fffu + ((u >> 16) & 1u);
  return (unsigned short)(u >> 16);
}
__device__ __forceinline__ float bf2f(unsigned short h) {
  return __builtin_bit_cast(float, ((unsigned)h) << 16);
}
__device__ __forceinline__ float sigm(float x) { return 1.f / (1.f + expf(-x)); }

__device__ __forceinline__ void st_agent(float* p, float v) {
  __hip_atomic_store(p, v, __ATOMIC_RELAXED, __HIP_MEMORY_SCOPE_AGENT);
}
__device__ __forceinline__ float ld_agent(const float* p) {
  return __hip_atomic_load((float*)p, __ATOMIC_RELAXED, __HIP_MEMORY_SCOPE_AGENT);
}
__device__ __forceinline__ void st_flag(int* p, int v) {
  __hip_atomic_store(p, v, __ATOMIC_RELEASE, __HIP_MEMORY_SCOPE_AGENT);
}
__device__ __forceinline__ int ld_flag(int* p) {
  return __hip_atomic_load(p, __ATOMIC_ACQUIRE, __HIP_MEMORY_SCOPE_AGENT);
}

// ---------------- embedding gather ----------------
__global__ void embed_kernel(const int* __restrict__ x, const float* __restrict__ tab,
                             float* __restrict__ emb) {
  int tok = blockIdx.x, tid = threadIdx.x;
  emb[tok * 256 + tid] = tab[x[tok] * 256 + tid];
}

// ---------------- pack x-part of lstm_W: Wxp[d][g*256+q] = lstm_W[g][d][q], d<256 ----------------
__global__ void pack_wx_kernel(const float* __restrict__ lstmW, float* __restrict__ Wxp) {
  int i = blockIdx.x * 256 + threadIdx.x;  // < 256*1024
  int d = i >> 10, n = i & 1023;
  int g = n >> 8, q = n & 255;
  Wxp[i] = lstmW[(g * 512 + d) * 256 + q];
}

// ---------------- generic f32 GEMM: C[M,N] = A[M,K]*B[K,N] + bias[N], opt relu ----------------
__global__ void __launch_bounds__(256) gemm_f32(const float* __restrict__ A,
                                                const float* __restrict__ Bm,
                                                const float* __restrict__ bias,
                                                float* __restrict__ C,
                                                int M, int N, int K, int relu) {
  __shared__ float As[16][65];
  __shared__ float Bs[16][65];
  int tid = threadIdx.x;
  int bm = blockIdx.y * 64;
  int bn = blockIdx.x * 64;
  int tx = tid & 15;   // n dir
  int ty = tid >> 4;   // m dir
  float acc[4][4] = {};
  for (int k0 = 0; k0 < K; k0 += 16) {
#pragma unroll
    for (int i = tid; i < 64 * 16; i += 256) {
      int r = i >> 4, kk = i & 15;
      As[kk][r] = A[(bm + r) * K + k0 + kk];
    }
#pragma unroll
    for (int i = tid; i < 16 * 64; i += 256) {
      int kk = i >> 6, cc = i & 63;
      Bs[kk][cc] = Bm[(k0 + kk) * N + bn + cc];
    }
    __syncthreads();
#pragma unroll
    for (int kk = 0; kk < 16; ++kk) {
      float a[4], bb[4];
#pragma unroll
      for (int i = 0; i < 4; ++i) a[i] = As[kk][ty + 16 * i];
#pragma unroll
      for (int j = 0; j < 4; ++j) bb[j] = Bs[kk][tx + 16 * j];
#pragma unroll
      for (int i = 0; i < 4; ++i)
#pragma unroll
        for (int j = 0; j < 4; ++j) acc[i][j] += a[i] * bb[j];
    }
    __syncthreads();
  }
#pragma unroll
  for (int i = 0; i < 4; ++i) {
    int r = bm + ty + 16 * i;
#pragma unroll
    for (int j = 0; j < 4; ++j) {
      int cc = bn + tx + 16 * j;
      float vv = acc[i][j] + bias[cc];
      if (relu) vv = fmaxf(vv, 0.f);
      C[r * N + cc] = vv;
    }
  }
}

// ---------------- QLSTM: 64 blocks = (b,g); Wh[g] bf16 in LDS; flag exchange per step ----------
__global__ void __launch_bounds__(256, 1) lstm_kernel(const float* __restrict__ lstmW,
                                                      const float* __restrict__ lstmTh,
                                                      const float* __restrict__ xw,
                                                      float* __restrict__ hb,
                                                      float* __restrict__ qbuf,
                                                      int* __restrict__ flags) {
  extern __shared__ char smem[];
  unsigned short* Wh = (unsigned short*)smem;        // [256][256] bf16
  float* hxs = (float*)(smem + 256 * 256 * 2);       // [256]
  float* wtot = hxs + 256;                           // [4]

  const int tid = threadIdx.x;
  const int b = blockIdx.x >> 2;
  const int g = blockIdx.x & 3;
  const int lane = tid & 63, wid = tid >> 6;

  // stage Wh[g] (h-part rows 256..511) as bf16
  for (int i = tid; i < 256 * 256; i += 256) {
    int d = i >> 8, q = i & 255;
    Wh[i] = f2bf(lstmW[(g * 512 + 256 + d) * 256 + q]);
  }
  float theta = lstmTh[g * 256 + tid];
  float cx = 0.f;
  hxs[tid] = 0.f;
  __syncthreads();

  int* flag_q = flags;        // [16][4]
  int* flag_h = flags + 64;   // [16]

  for (int t = 0; t < 256; ++t) {
    // z = xw + hx*Wh
    float acc = xw[(b * 256 + t) * 1024 + g * 256 + tid];
#pragma unroll 8
    for (int d = 0; d < 256; ++d) acc += hxs[d] * bf2f(Wh[(d << 8) + tid]);
    float c = cosf(acc + theta);

    // block-wide inclusive product scan over 256 lanes
    float v = c;
#pragma unroll
    for (int off = 1; off < 64; off <<= 1) {
      float o = __shfl_up(v, off, 64);
      if (lane >= off) v *= o;
    }
    __syncthreads();  // previous iteration's wtot readers done
    if (lane == 63) wtot[wid] = v;
    __syncthreads();
    float pre = 1.f;
    for (int w = 0; w < wid; ++w) pre *= wtot[w];
    v *= pre;  // gate pre-activation q-value

    st_agent(&qbuf[(b * 4 + g) * 256 + tid], v);
    __threadfence();
    __syncthreads();
    if (tid == 0) st_flag(&flag_q[b * 4 + g], t + 1);

    if (g == 0) {  // leader: combine gates, update cx/hx
      if (tid < 3) {
        while (ld_flag(&flag_q[b * 4 + 1 + tid]) < t + 1) __builtin_amdgcn_s_sleep(2);
      }
      __syncthreads();
      float q1 = ld_agent(&qbuf[(b * 4 + 1) * 256 + tid]);
      float q2 = ld_agent(&qbuf[(b * 4 + 2) * 256 + tid]);
      float q3 = ld_agent(&qbuf[(b * 4 + 3) * 256 + tid]);
      float fg = sigm(v);
      float ig = sigm(q1);
      float gg = tanhf(q2);
      float og = sigm(q3);
      cx = fg * cx + ig * gg;
      float hv = og * tanhf(cx);
      st_agent(&hb[(b * 256 + t) * 256 + tid], hv);
      __threadfence();
      __syncthreads();
      if (tid == 0) st_flag(&flag_h[b], t + 1);
    }

    if (tid == 0) {
      while (ld_flag(&flag_h[b]) < t + 1) __builtin_amdgcn_s_sleep(2);
    }
    __syncthreads();
    hxs[tid] = ld_agent(&hb[(b * 256 + t) * 256 + tid]);
    __syncthreads();
  }
}

// ---------------- h += sinusoidal PE ----------------
__global__ void pe_add_kernel(float* __restrict__ h) {
  int tok = blockIdx.x, tid = threadIdx.x;
  int s = tok & 255;
  int j = tid >> 1;
  float div = expf((float)j * -0.07195578415622253f);  // 2j * (-ln(10000)/256)
  float ang = (float)s * div;
  float pe = (tid & 1) ? cosf(ang) : sinf(ang);
  h[tok * 256 + tid] += pe;
}

// ---------------- qproj: out = cumprod(cos(h + theta)) along E ----------------
__global__ void qproj_kernel(const float* __restrict__ hin, const float* __restrict__ theta,
                             float* __restrict__ out) {
  __shared__ float wtot[4];
  int tok = blockIdx.x, tid = threadIdx.x, lane = tid & 63, wid = tid >> 6;
  float v = cosf(hin[tok * 256 + tid] + theta[tid]);
#pragma unroll
  for (int off = 1; off < 64; off <<= 1) {
    float o = __shfl_up(v, off, 64);
    if (lane >= off) v *= o;
  }
  if (lane == 63) wtot[wid] = v;
  __syncthreads();
  float pre = 1.f;
  for (int w = 0; w < wid; ++w) pre *= wtot[w];
  out[tok * 256 + tid] = v * pre;
}

// ---------------- attention: one block per (head, batch); wave-per-row ----------------
__global__ void __launch_bounds__(256, 1) attn_kernel(const float* __restrict__ qb,
                                                      const float* __restrict__ kb,
                                                      const float* __restrict__ vb,
                                                      float* __restrict__ attnout) {
  extern __shared__ float sm[];
  float* Qs = sm;                 // [256][33]
  float* Ks = Qs + 256 * 33;
  float* Vs = Ks + 256 * 33;
  float* ps = Vs + 256 * 33;      // [4][256]
  int hd = blockIdx.x, b = blockIdx.y;
  int tid = threadIdx.x, lane = tid & 63, wid = tid >> 6;
  const float scale = 0.17677669529663687f;  // 1/sqrt(32)

  for (int i = tid; i < 256 * 32; i += 256) {
    int r = i >> 5, d = i & 31;
    int src = (b * 256 + r) * 256 + hd * 32 + d;
    Qs[r * 33 + d] = qb[src];
    Ks[r * 33 + d] = kb[src];
    Vs[r * 33 + d] = vb[src];
  }
  __syncthreads();

  float* pw = ps + wid * 256;
  for (int r = wid; r < 256; r += 4) {
    float qreg[32];
#pragma unroll
    for (int d = 0; d < 32; ++d) qreg[d] = Qs[r * 33 + d];
    float s[4];
#pragma unroll
    for (int j = 0; j < 4; ++j) {
      int k = lane + 64 * j;
      float a = 0.f;
#pragma unroll
      for (int d = 0; d < 32; ++d) a += qreg[d] * Ks[k * 33 + d];
      s[j] = a * scale;
    }
    float m = fmaxf(fmaxf(s[0], s[1]), fmaxf(s[2], s[3]));
#pragma unroll
    for (int off = 32; off; off >>= 1) m = fmaxf(m, __shfl_xor(m, off, 64));
    float p[4], sum = 0.f;
#pragma unroll
    for (int j = 0; j < 4; ++j) { p[j] = expf(s[j] - m); sum += p[j]; }
#pragma unroll
    for (int off = 32; off; off >>= 1) sum += __shfl_xor(sum, off, 64);
    float inv = 1.f / sum;
#pragma unroll
    for (int j = 0; j < 4; ++j) pw[lane + 64 * j] = p[j] * inv;
    // same-wave LDS write->read: compiler inserts lgkmcnt wait
    int d = lane & 31, half = lane >> 5;
    float a = 0.f;
#pragma unroll 8
    for (int i2 = 0; i2 < 128; ++i2) {
      int k = half * 128 + i2;
      a += pw[k] * Vs[k * 33 + d];
    }
    a += __shfl_down(a, 32, 64);
    if (lane < 32) attnout[(b * 256 + r) * 256 + hd * 32 + d] = a;
  }
}

// ---------------- layernorm(h + delta) -> h ----------------
__global__ void ln_kernel(float* __restrict__ hio, const float* __restrict__ delta,
                          const float* __restrict__ gamma, const float* __restrict__ beta) {
  __shared__ float red[16];
  int tok = blockIdx.x, tid = threadIdx.x, lane = tid & 63, wid = tid >> 6;
  float v = hio[tok * 256 + tid] + delta[tok * 256 + tid];
  float s1 = v, s2 = v * v;
#pragma unroll
  for (int off = 32; off; off >>= 1) {
    s1 += __shfl_xor(s1, off, 64);
    s2 += __shfl_xor(s2, off, 64);
  }
  if (lane == 0) { red[wid] = s1; red[wid + 8] = s2; }
  __syncthreads();
  float t1 = red[0] + red[1] + red[2] + red[3];
  float t2 = red[8] + red[9] + red[10] + red[11];
  float mean = t1 * (1.f / 256.f);
  float var = t2 * (1.f / 256.f) - mean * mean;
  float w = rsqrtf(var + 1e-5f);
  hio[tok * 256 + tid] = (v - mean) * w * gamma[tid] + beta[tid];
}

// ---------------- mean pool over S + classifier ----------------
__global__ void pool_cls_kernel(const float* __restrict__ h, const float* __restrict__ clsW,
                                const float* __restrict__ clsb, float* __restrict__ out) {
  __shared__ float pl[256];
  __shared__ float red[8];
  int b = blockIdx.x, tid = threadIdx.x, lane = tid & 63, wid = tid >> 6;
  float s = 0.f;
  for (int t = 0; t < 256; ++t) s += h[(b * 256 + t) * 256 + tid];
  pl[tid] = s * (1.f / 256.f);
  __syncthreads();
  for (int c = 0; c < 4; ++c) {
    float v = pl[tid] * clsW[tid * 4 + c];
#pragma unroll
    for (int off = 32; off; off >>= 1) v += __shfl_xor(v, off, 64);
    if (lane == 0) red[wid] = v;
    __syncthreads();
    if (tid == 0) out[b * 4 + c] = red[0] + red[1] + red[2] + red[3] + clsb[c];
    __syncthreads();
  }
}

extern "C" void kernel_launch(void* const* d_in, const int* in_sizes, int n_in,
                              void* d_out, int out_size, void* d_ws, size_t ws_size,
                              hipStream_t stream) {
  const int* x = (const int*)d_in[0];
  const float* token_emb = (const float*)d_in[1];
  const float* lstm_W = (const float*)d_in[2];
  const float* lstm_b = (const float*)d_in[3];
  const float* lstm_th = (const float*)d_in[4];
  const float* ln1_g = (const float*)d_in[5];
  const float* ln1_b = (const float*)d_in[6];
  const float* ln2_g = (const float*)d_in[7];
  const float* ln2_b = (const float*)d_in[8];
  const float* qkv_th = (const float*)d_in[9];
  const float* comb_W = (const float*)d_in[10];
  const float* comb_b = (const float*)d_in[11];
  const float* ffn_th = (const float*)d_in[12];
  const float* lin1_W = (const float*)d_in[13];
  const float* lin1_b = (const float*)d_in[14];
  const float* lin2_W = (const float*)d_in[15];
  const float* lin2_b = (const float*)d_in[16];
  const float* cls_W = (const float*)d_in[17];
  const float* cls_b = (const float*)d_in[18];

  float* ws = (float*)d_ws;
  float* emb = ws;                       // 1M floats (later: attnout)
  float* xw = ws + 1048576;              // 4M (later: ffh)
  float* hb = ws + 5242880;              // 1M
  float* qq = ws + 6291456;              // 1M
  float* kk = ws + 7340032;              // 1M
  float* vv = ws + 8388608;              // 1M (later: ffq)
  float* tmp = ws + 9437184;             // 1M
  float* Wxp = ws + 10485760;            // 256K
  float* qbuf = ws + 10747904;           // 16K
  int* flags = (int*)(ws + 10764288);    // 80 ints

  const int LSTM_LDS = 256 * 256 * 2 + 256 * 4 + 64;          // 132160 B
  const int ATT_LDS = (3 * 256 * 33 + 4 * 256) * 4;           // 105472 B
  (void)hipFuncSetAttribute(reinterpret_cast<const void*>(lstm_kernel),
                            hipFuncAttributeMaxDynamicSharedMemorySize, LSTM_LDS);
  (void)hipFuncSetAttribute(reinterpret_cast<const void*>(attn_kernel),
                            hipFuncAttributeMaxDynamicSharedMemorySize, ATT_LDS);

  hipMemsetAsync(flags, 0, 512, stream);

  embed_kernel<<<4096, 256, 0, stream>>>(x, token_emb, emb);
  pack_wx_kernel<<<1024, 256, 0, stream>>>(lstm_W, Wxp);
  // xw[token][g*256+q] = emb . Wx + lstm_b
  gemm_f32<<<dim3(16, 64), 256, 0, stream>>>(emb, Wxp, lstm_b, xw, 4096, 1024, 256, 0);
  lstm_kernel<<<64, 256, LSTM_LDS, stream>>>(lstm_W, lstm_th, xw, hb, qbuf, flags);
  pe_add_kernel<<<4096, 256, 0, stream>>>(hb);

  for (int l = 0; l < 2; ++l) {
    qproj_kernel<<<4096, 256, 0, stream>>>(hb, qkv_th + (l * 3 + 0) * 256, qq);
    qproj_kernel<<<4096, 256, 0, stream>>>(hb, qkv_th + (l * 3 + 1) * 256, kk);
    qproj_kernel<<<4096, 256, 0, stream>>>(hb, qkv_th + (l * 3 + 2) * 256, vv);
    attn_kernel<<<dim3(8, 16), 256, ATT_LDS, stream>>>(qq, kk, vv, emb);
    gemm_f32<<<dim3(4, 64), 256, 0, stream>>>(emb, comb_W + l * 65536, comb_b + l * 256,
                                              tmp, 4096, 256, 256, 0);
    ln_kernel<<<4096, 256, 0, stream>>>(hb, tmp, ln1_g + l * 256, ln1_b + l * 256);
    qproj_kernel<<<4096, 256, 0, stream>>>(hb, ffn_th + l * 256, vv);
    gemm_f32<<<dim3(16, 64), 256, 0, stream>>>(vv, lin1_W + l * 262144, lin1_b + l * 1024,
                                               xw, 4096, 1024, 256, 1);
    gemm_f32<<<dim3(4, 64), 256, 0, stream>>>(xw, lin2_W + l * 262144, lin2_b + l * 256,
                                              tmp, 4096, 256, 1024, 0);
    ln_kernel<<<4096, 256, 0, stream>>>(hb, tmp, ln2_g + l * 256, ln2_b + l * 256);
  }

  pool_cls_kernel<<<16, 256, 0, stream>>>(hb, cls_W, cls_b, (float*)d_out);
}